// Round 5
// baseline (190.839 us; speedup 1.0000x reference)
//
#include <hip/hip_runtime.h>
#include <stdint.h>

// Problem constants (from setup_inputs; harness always uses these)
#define BB   2
#define CC   32      // input channels
#define TT   64      // input T
#define HWH  4096    // H*W = 64*64
#define NN   512     // coords per batch
#define CFF  32      // feat channels
#define CHH  16      // projection channels
#define TOUT 400     // featT == orgt == 400
#define LL   (TOUT*NN)  // 204800

__device__ __forceinline__ void lerp_coeff(int to, int& i0, int& i1, float& w){
  const float step = (float)(63.0 / 399.0);   // matches python (T-1)/(out_t-1) in f32
  float pos = (float)to * step;
  i0 = (int)floorf(pos);
  if (i0 > TT - 1) i0 = TT - 1;
  i1 = i0 + 1; if (i1 > TT - 1) i1 = TT - 1;
  w = pos - (float)i0;
}

// ---------------- Kernel A (fused): r = Wr.x + br  AND  Z = Weff.x[coord] + bz ----------------
// Block = (b, t, quarter of hw). While streaming x for r, matched gather columns are staged
// into LDS via per-block linked-list coord map; phase 2 projects them with Weff = W1.Wf.
// LDS ~78 KB -> 2 blocks/CU, exactly what the 512-block grid needs (256 CUs).
__global__ __launch_bounds__(256) void k_r(const float* __restrict__ x, const float* __restrict__ Wr,
                                           const float* __restrict__ br, const int* __restrict__ coord,
                                           const float* __restrict__ Wf, const float* __restrict__ bfv,
                                           const float* __restrict__ W1, const float* __restrict__ b1,
                                           float* __restrict__ r, float* __restrict__ Z,
                                           float* __restrict__ stats){
  __shared__ float sCol[512 * 33];   // staged columns, +1 pad -> bank (slot+c)%32
  __shared__ int   sHead[1024];      // chain head per local hw
  __shared__ int   sNext[512];       // chain next per n
  __shared__ int   sColHw[512];      // slot -> local hw
  __shared__ float sWT[CC][CHH];     // Weff^T: [c][o]
  __shared__ float sbz[CHH];         // W1.bf + b1
  __shared__ int   sCnt;

  int q = blockIdx.x & 3, t = (blockIdx.x >> 2) & 63, b = (int)blockIdx.x >> 8;
  if (blockIdx.x == 0 && threadIdx.x < 32) stats[threadIdx.x] = 0.f;

  // phase 0a: Weff = W1 . Wf (16x32), fused bias
  for (int i = threadIdx.x; i < CHH * CC; i += 256){
    int o = i >> 5, c = i & 31;
    float v = 0.f;
    #pragma unroll
    for (int k = 0; k < CFF; ++k) v += W1[o * CFF + k] * Wf[k * CC + c];
    sWT[c][o] = v;
  }
  if (threadIdx.x < CHH){
    float v = b1[threadIdx.x];
    #pragma unroll
    for (int k = 0; k < CFF; ++k) v += W1[threadIdx.x * CFF + k] * bfv[k];
    sbz[threadIdx.x] = v;
  }
  // phase 0b: coord chains for this block's quarter
  #pragma unroll
  for (int j = 0; j < 4; ++j) sHead[threadIdx.x * 4 + j] = -1;
  if (threadIdx.x == 0) sCnt = 0;
  __syncthreads();
  #pragma unroll
  for (int k = 0; k < 2; ++k){
    int n  = (int)threadIdx.x + 256 * k;
    int hh = coord[(b * NN + n) * 2], ww = coord[(b * NN + n) * 2 + 1];
    int hw = hh * 64 + ww;
    if ((hw >> 10) == q) sNext[n] = atomicExch(&sHead[hw & 1023], n);
  }
  __syncthreads();
  int lhw0 = (int)threadIdx.x * 4;
  int slot[4];
  #pragma unroll
  for (int j = 0; j < 4; ++j){
    bool m = (sHead[lhw0 + j] != -1);
    slot[j] = m ? atomicAdd(&sCnt, 1) : -1;
    if (m) sColHw[slot[j]] = lhw0 + j;
  }

  // phase 1: stream x -> r accumulation + predicated LDS staging of matched columns
  int hw0 = q * 1024 + lhw0;
  float br0 = br[0];
  float4 acc = make_float4(br0, br0, br0, br0);
  const float* xp = x + ((size_t)(b * CC) * TT + t) * HWH + hw0;
  #pragma unroll
  for (int c = 0; c < CC; ++c){
    float4 v = *reinterpret_cast<const float4*>(xp + (size_t)c * TT * HWH);
    float w = Wr[c];
    acc.x += w * v.x;  acc.y += w * v.y;  acc.z += w * v.z;  acc.w += w * v.w;
    if (slot[0] >= 0) sCol[slot[0] * 33 + c] = v.x;
    if (slot[1] >= 0) sCol[slot[1] * 33 + c] = v.y;
    if (slot[2] >= 0) sCol[slot[2] * 33 + c] = v.z;
    if (slot[3] >= 0) sCol[slot[3] * 33 + c] = v.w;
  }
  *reinterpret_cast<float4*>(r + ((size_t)(b * TT + t)) * HWH + hw0) = acc;

  // phase 2: project staged columns, write Z for every n in the chain
  __syncthreads();
  int ncols = sCnt;
  for (int k2 = threadIdx.x; k2 < ncols; k2 += 256){
    float z[CHH];
    #pragma unroll
    for (int o = 0; o < CHH; ++o) z[o] = sbz[o];
    #pragma unroll
    for (int c = 0; c < CC; ++c){
      float xc = sCol[k2 * 33 + c];
      #pragma unroll
      for (int o4 = 0; o4 < CHH; o4 += 4){
        const float4 w4 = *reinterpret_cast<const float4*>(&sWT[c][o4]);  // broadcast
        z[o4]   += w4.x * xc;  z[o4+1] += w4.y * xc;
        z[o4+2] += w4.z * xc;  z[o4+3] += w4.w * xc;
      }
    }
    float4 z0 = make_float4(z[0],  z[1],  z[2],  z[3]);
    float4 z1 = make_float4(z[4],  z[5],  z[6],  z[7]);
    float4 z2 = make_float4(z[8],  z[9],  z[10], z[11]);
    float4 z3 = make_float4(z[12], z[13], z[14], z[15]);
    int n = sHead[sColHw[k2]];
    while (n != -1){
      float* zp = Z + ((size_t)((b * TT + t) * NN + n)) * CHH;
      *reinterpret_cast<float4*>(zp)      = z0;
      *reinterpret_cast<float4*>(zp + 4)  = z1;
      *reinterpret_cast<float4*>(zp + 8)  = z2;
      *reinterpret_cast<float4*>(zp + 12) = z3;
      n = sNext[n];
    }
  }
}

// ---------------- Kernel B: result = lerp_t(r) ----------------
__global__ __launch_bounds__(256) void k_result(const float* __restrict__ r, float* __restrict__ outR){
  int tid = blockIdx.x * 256 + threadIdx.x;   // 819200 threads, 4 hw each
  int hw0  = (tid & 1023) << 2;
  int rest = tid >> 10;                       // 0..799 = b*400+to
  int b  = rest >= TOUT ? 1 : 0;
  int to = rest - b * TOUT;
  int i0, i1; float w;
  lerp_coeff(to, i0, i1, w);
  float4 a = *reinterpret_cast<const float4*>(r + ((size_t)(b * TT + i0)) * HWH + hw0);
  float4 c = *reinterpret_cast<const float4*>(r + ((size_t)(b * TT + i1)) * HWH + hw0);
  float4 o;
  o.x = a.x + w * (c.x - a.x);
  o.y = a.y + w * (c.y - a.y);
  o.z = a.z + w * (c.z - a.z);
  o.w = a.w + w * (c.w - a.w);
  *reinterpret_cast<float4*>(outR + ((size_t)(b * TOUT + to)) * HWH + hw0) = o;
}

// ---------------- Kernel D: moment accumulation: h_to = lerp(Z), need sum h, sum h^2 ----------------
// A1[o] = sum_t q_t z_t[o];  A2[o] = sum_t a_t z_t[o]^2 + c_t z_t[o] z_{t+1}[o]
__global__ __launch_bounds__(256) void k_mom(const float* __restrict__ Z, float* __restrict__ stats){
  __shared__ float sco[192];        // q[64], a[64], c[64]
  __shared__ float red[4][32];
  if (threadIdx.x < 192) sco[threadIdx.x] = 0.f;
  __syncthreads();
  for (int to = threadIdx.x; to < TOUT; to += 256){
    int i0, i1; float w;
    lerp_coeff(to, i0, i1, w);
    if (i1 == i0){
      atomicAdd(&sco[i0], 1.f);  atomicAdd(&sco[64 + i0], 1.f);
    } else {
      float u = 1.f - w;
      atomicAdd(&sco[i0], u);        atomicAdd(&sco[64 + i0], u * u);
      atomicAdd(&sco[i1], w);        atomicAdd(&sco[64 + i1], w * w);
      atomicAdd(&sco[128 + i0], 2.f * w * u);
    }
  }
  __syncthreads();
  int t = threadIdx.x & 63;                         // lane == t (for the shfl cross-term)
  int e = blockIdx.x * 4 + ((int)threadIdx.x >> 6); // (b,n) 0..1023
  int b = e >> 9, n = e & 511;
  const float* zp = Z + ((size_t)((b * TT + t) * NN + n)) * CHH;
  float z[CHH];
  #pragma unroll
  for (int c = 0; c < CHH; c += 4){
    float4 v = *reinterpret_cast<const float4*>(zp + c);
    z[c] = v.x; z[c+1] = v.y; z[c+2] = v.z; z[c+3] = v.w;
  }
  float qt = sco[t], at = sco[64 + t], ct = sco[128 + t];   // ct==0 at t=63 structurally
  float v1[CHH], v2[CHH];
  #pragma unroll
  for (int o = 0; o < CHH; ++o){
    float zn = __shfl_down(z[o], 1, 64);            // z at t+1 (same b,n)
    v1[o] = qt * z[o];
    v2[o] = at * z[o] * z[o] + ct * z[o] * zn;
  }
  #pragma unroll
  for (int o = 0; o < CHH; ++o){
    #pragma unroll
    for (int s = 32; s > 0; s >>= 1){
      v1[o] += __shfl_down(v1[o], s, 64);
      v2[o] += __shfl_down(v2[o], s, 64);
    }
  }
  int wave = threadIdx.x >> 6, lane = threadIdx.x & 63;
  if (lane == 0){
    #pragma unroll
    for (int o = 0; o < CHH; ++o){ red[wave][o] = v1[o]; red[wave][16 + o] = v2[o]; }
  }
  __syncthreads();
  if (threadIdx.x < 32){
    float v = red[0][threadIdx.x] + red[1][threadIdx.x] + red[2][threadIdx.x] + red[3][threadIdx.x];
    atomicAdd(stats + threadIdx.x, v);
  }
}

// ---------------- Kernel E: h = lerp(Z) -> BN -> ReLU -> W2 -> out ----------------
__global__ __launch_bounds__(256) void k_out(const float* __restrict__ Z, const float* __restrict__ W2,
                                             const float* __restrict__ b2, const float* __restrict__ gamma,
                                             const float* __restrict__ beta, const float* __restrict__ stats,
                                             float* __restrict__ out){
  __shared__ float sW2[CHH][CHH];
  __shared__ float sb2[CHH], ssc[CHH], ssh[CHH];
  for (int i = threadIdx.x; i < CHH * CHH; i += 256) sW2[i >> 4][i & 15] = W2[i];
  if (threadIdx.x < CHH){
    int o = threadIdx.x;
    const float inv = 1.0f / (float)(BB * (long long)LL);   // 1/409600
    float mu  = stats[o] * inv;
    float var = stats[16 + o] * inv - mu * mu;
    float sc  = gamma[o] * (1.0f / sqrtf(var + 1e-5f));
    ssc[o] = sc;
    ssh[o] = beta[o] - mu * sc;
    sb2[o] = b2[o];
  }
  __syncthreads();
  // XCD-contiguous block swizzle: 1600 blocks -> 8 XCDs x 200 contiguous (L2 reuse of Z slabs)
  int xcd = blockIdx.x & 7, loc = blockIdx.x >> 3;
  int eb = xcd * 200 + loc;
  int li  = eb * 256 + (int)threadIdx.x;   // 0..409599
  int b   = li / LL;
  int rem = li - b * LL;
  int to  = rem >> 9;
  int n   = rem & 511;
  int i0, i1; float w;
  lerp_coeff(to, i0, i1, w);
  const float* z0 = Z + ((size_t)((b * TT + i0) * NN + n)) * CHH;
  const float* z1 = Z + ((size_t)((b * TT + i1) * NN + n)) * CHH;
  float hr[CHH];
  #pragma unroll
  for (int c = 0; c < CHH; c += 4){
    float4 a = *reinterpret_cast<const float4*>(z0 + c);
    float4 d = *reinterpret_cast<const float4*>(z1 + c);
    float h0 = a.x + w * (d.x - a.x);
    float h1 = a.y + w * (d.y - a.y);
    float h2 = a.z + w * (d.z - a.z);
    float h3 = a.w + w * (d.w - a.w);
    hr[c]   = fmaxf(h0 * ssc[c]   + ssh[c],   0.0f);
    hr[c+1] = fmaxf(h1 * ssc[c+1] + ssh[c+1], 0.0f);
    hr[c+2] = fmaxf(h2 * ssc[c+2] + ssh[c+2], 0.0f);
    hr[c+3] = fmaxf(h3 * ssc[c+3] + ssh[c+3], 0.0f);
  }
  #pragma unroll
  for (int o2 = 0; o2 < CHH; ++o2){
    float v = sb2[o2];
    #pragma unroll
    for (int o = 0; o < CHH; ++o) v += sW2[o2][o] * hr[o];
    out[((size_t)(b * CHH + o2)) * LL + rem] = v;
  }
}

extern "C" void kernel_launch(void* const* d_in, const int* in_sizes, int n_in,
                              void* d_out, int out_size, void* d_ws, size_t ws_size,
                              hipStream_t stream){
  (void)in_sizes; (void)n_in; (void)out_size; (void)ws_size;
  const float* x     = (const float*)d_in[0];
  const int*   coord = (const int*)d_in[1];
  const float* Wf    = (const float*)d_in[2];
  const float* bfv   = (const float*)d_in[3];
  const float* Wr    = (const float*)d_in[4];
  const float* br    = (const float*)d_in[5];
  const float* W1    = (const float*)d_in[6];
  const float* b1    = (const float*)d_in[7];
  const float* gamma = (const float*)d_in[8];
  const float* beta  = (const float*)d_in[9];
  const float* W2    = (const float*)d_in[10];
  const float* b2    = (const float*)d_in[11];

  float* ws    = (float*)d_ws;
  float* r     = ws;                          // 524288 f32  (2 MB)
  float* Z     = ws + 524288;                 // 1048576 f32 (4 MB)
  float* stats = ws + 524288 + 1048576;       // 32 f32: [A1(16), A2(16)]

  float* out  = (float*)d_out;                // [B,16,L] = 6,553,600 f32
  float* outR = out + (size_t)BB * CHH * LL;  // [B,1,400,64,64] = 3,276,800 f32

  k_r     <<<512,  256, 0, stream>>>(x, Wr, br, coord, Wf, bfv, W1, b1, r, Z, stats);
  k_result<<<3200, 256, 0, stream>>>(r, outR);
  k_mom   <<<256,  256, 0, stream>>>(Z, stats);
  k_out   <<<1600, 256, 0, stream>>>(Z, W2, b2, gamma, beta, stats, out);
}

// Round 6
// 179.326 us; speedup vs baseline: 1.0642x; 1.0642x over previous
//
#include <hip/hip_runtime.h>
#include <stdint.h>

// Problem constants (from setup_inputs; harness always uses these)
#define BB   2
#define CC   32      // input channels
#define TT   64      // input T
#define HWH  4096    // H*W = 64*64
#define NN   512     // coords per batch
#define CFF  32      // feat channels
#define CHH  16      // projection channels
#define TOUT 400     // featT == orgt == 400
#define LL   (TOUT*NN)  // 204800

__device__ __forceinline__ void lerp_coeff(int to, int& i0, int& i1, float& w){
  const float step = (float)(63.0 / 399.0);   // matches python (T-1)/(out_t-1) in f32
  float pos = (float)to * step;
  i0 = (int)floorf(pos);
  if (i0 > TT - 1) i0 = TT - 1;
  i1 = i0 + 1; if (i1 > TT - 1) i1 = TT - 1;
  w = pos - (float)i0;
}

// ---------------- Kernel A: r[b][t][hw] = sum_c Wr[c]*x[b][c][t][hw] + br ----------------
// Pure streaming kernel: low VGPR, high occupancy — do NOT fuse scatter work in here (R5 lesson).
// Block 0 also zeroes the 32 stats accumulators (consumed by k_rm 2 dispatches later).
__global__ __launch_bounds__(256) void k_r(const float* __restrict__ x, const float* __restrict__ Wr,
                                           const float* __restrict__ br, float* __restrict__ r,
                                           float* __restrict__ stats){
  if (blockIdx.x == 0 && threadIdx.x < 32) stats[threadIdx.x] = 0.f;
  int tid = blockIdx.x * 256 + threadIdx.x;   // 131072 threads, 4 hw each
  int hw0 = (tid & 1023) << 2;
  int t   = (tid >> 10) & 63;
  int b   = tid >> 16;
  float br0 = br[0];
  float4 acc = make_float4(br0, br0, br0, br0);
  const float* xp = x + ((size_t)(b * CC) * TT + t) * HWH + hw0;
  #pragma unroll
  for (int c = 0; c < CC; ++c){
    float4 v = *reinterpret_cast<const float4*>(xp + (size_t)c * TT * HWH);
    float w = Wr[c];
    acc.x += w * v.x;  acc.y += w * v.y;  acc.z += w * v.z;  acc.w += w * v.w;
  }
  *reinterpret_cast<float4*>(r + ((size_t)(b * TT + t)) * HWH + hw0) = acc;
}

// ---------------- Kernel C: Z[b][t][n][o16] = Weff . x[b,:,t,coord] + (W1.bf + b1) ----------------
// Weff = W1(16x32) . Wf(32x32), computed once per block in LDS (cheap: 16K FMA / 256 thr).
// 4 lanes per element; each lane gathers 8 input channels, shares via __shfl, emits 4 outputs.
// Runs after k_r so x is L3-resident (R5 counters: FETCH 38MB < |x|).
__global__ __launch_bounds__(256) void k_z(const float* __restrict__ x, const int* __restrict__ coord,
                                           const float* __restrict__ Wf, const float* __restrict__ bfv,
                                           const float* __restrict__ W1, const float* __restrict__ b1,
                                           float* __restrict__ Z){
  __shared__ float sWT[CC][CHH];    // Weff transposed: [c][o]
  __shared__ float scz[CHH];        // fused bias  W1.bf + b1
  for (int i = threadIdx.x; i < CHH * CC; i += 256){
    int o = i >> 5, c = i & 31;
    float v = 0.f;
    #pragma unroll
    for (int k = 0; k < CFF; ++k) v += W1[o * CFF + k] * Wf[k * CC + c];
    sWT[c][o] = v;
  }
  if (threadIdx.x < CHH){
    float v = b1[threadIdx.x];
    #pragma unroll
    for (int k = 0; k < CFF; ++k) v += W1[threadIdx.x * CFF + k] * bfv[k];
    scz[threadIdx.x] = v;
  }
  __syncthreads();
  int lane = threadIdx.x & 63;
  int sub  = threadIdx.x & 3;                        // quarter (channels in, outputs out)
  int e = blockIdx.x * 64 + ((int)threadIdx.x >> 2); // element 0..65535 = (b,t,n)
  int n = e & 511, t = (e >> 9) & 63, b = e >> 15;
  int h  = coord[(b * NN + n) * 2 + 0];
  int wq = coord[(b * NN + n) * 2 + 1];
  int hw = h * 64 + wq;
  const float* xp = x + (((size_t)(b * CC + sub * 8)) * TT + t) * HWH + hw;
  float xv[8];
  #pragma unroll
  for (int j = 0; j < 8; ++j) xv[j] = xp[(size_t)j * (TT * HWH)];
  float acc0 = scz[sub * 4], acc1 = scz[sub * 4 + 1], acc2 = scz[sub * 4 + 2], acc3 = scz[sub * 4 + 3];
  int grp = lane & ~3;
  #pragma unroll
  for (int j = 0; j < 8; ++j){
    #pragma unroll
    for (int src = 0; src < 4; ++src){
      float xc = __shfl(xv[j], grp + src, 64);   // channel c = src*8+j of this element
      int c = src * 8 + j;
      const float4 w4 = *reinterpret_cast<const float4*>(&sWT[c][sub * 4]);
      acc0 += w4.x * xc;  acc1 += w4.y * xc;  acc2 += w4.z * xc;  acc3 += w4.w * xc;
    }
  }
  *reinterpret_cast<float4*>(Z + ((size_t)((b * TT + t) * NN + n)) * CHH + sub * 4)
      = make_float4(acc0, acc1, acc2, acc3);
}

// ---------------- Kernel B+D merged: result lerp (blocks 0..3199) | moment accum (3200..3455) ----------------
// Moment part: A1[o] = sum_t q_t z_t[o];  A2[o] = sum_t a_t z_t[o]^2 + c_t z_t[o] z_{t+1}[o]
__global__ __launch_bounds__(256) void k_rm(const float* __restrict__ r, float* __restrict__ outR,
                                            const float* __restrict__ Z, float* __restrict__ stats){
  if (blockIdx.x < 3200){
    // ------- result = lerp_t(r) -------
    int tid = blockIdx.x * 256 + threadIdx.x;   // 819200 threads, 4 hw each
    int hw0  = (tid & 1023) << 2;
    int rest = tid >> 10;                       // 0..799 = b*400+to
    int b  = rest >= TOUT ? 1 : 0;
    int to = rest - b * TOUT;
    int i0, i1; float w;
    lerp_coeff(to, i0, i1, w);
    float4 a = *reinterpret_cast<const float4*>(r + ((size_t)(b * TT + i0)) * HWH + hw0);
    float4 c = *reinterpret_cast<const float4*>(r + ((size_t)(b * TT + i1)) * HWH + hw0);
    float4 o;
    o.x = a.x + w * (c.x - a.x);
    o.y = a.y + w * (c.y - a.y);
    o.z = a.z + w * (c.z - a.z);
    o.w = a.w + w * (c.w - a.w);
    *reinterpret_cast<float4*>(outR + ((size_t)(b * TOUT + to)) * HWH + hw0) = o;
    return;
  }
  // ------- moment accumulation -------
  __shared__ float sco[192];        // q[64], a[64], c[64]
  __shared__ float red[4][32];
  if (threadIdx.x < 192) sco[threadIdx.x] = 0.f;
  __syncthreads();
  for (int to = threadIdx.x; to < TOUT; to += 256){
    int i0, i1; float w;
    lerp_coeff(to, i0, i1, w);
    if (i1 == i0){
      atomicAdd(&sco[i0], 1.f);  atomicAdd(&sco[64 + i0], 1.f);
    } else {
      float u = 1.f - w;
      atomicAdd(&sco[i0], u);        atomicAdd(&sco[64 + i0], u * u);
      atomicAdd(&sco[i1], w);        atomicAdd(&sco[64 + i1], w * w);
      atomicAdd(&sco[128 + i0], 2.f * w * u);
    }
  }
  __syncthreads();
  int t = threadIdx.x & 63;                                  // lane == t (shfl cross-term)
  int e = (blockIdx.x - 3200) * 4 + ((int)threadIdx.x >> 6); // (b,n) 0..1023
  int b = e >> 9, n = e & 511;
  const float* zp = Z + ((size_t)((b * TT + t) * NN + n)) * CHH;
  float z[CHH];
  #pragma unroll
  for (int c = 0; c < CHH; c += 4){
    float4 v = *reinterpret_cast<const float4*>(zp + c);
    z[c] = v.x; z[c+1] = v.y; z[c+2] = v.z; z[c+3] = v.w;
  }
  float qt = sco[t], at = sco[64 + t], ct = sco[128 + t];   // ct==0 at t=63 structurally
  float v1[CHH], v2[CHH];
  #pragma unroll
  for (int o = 0; o < CHH; ++o){
    float zn = __shfl_down(z[o], 1, 64);            // z at t+1 (same b,n)
    v1[o] = qt * z[o];
    v2[o] = at * z[o] * z[o] + ct * z[o] * zn;
  }
  #pragma unroll
  for (int o = 0; o < CHH; ++o){
    #pragma unroll
    for (int s = 32; s > 0; s >>= 1){
      v1[o] += __shfl_down(v1[o], s, 64);
      v2[o] += __shfl_down(v2[o], s, 64);
    }
  }
  int wave = threadIdx.x >> 6, lane = threadIdx.x & 63;
  if (lane == 0){
    #pragma unroll
    for (int o = 0; o < CHH; ++o){ red[wave][o] = v1[o]; red[wave][16 + o] = v2[o]; }
  }
  __syncthreads();
  if (threadIdx.x < 32){
    float v = red[0][threadIdx.x] + red[1][threadIdx.x] + red[2][threadIdx.x] + red[3][threadIdx.x];
    atomicAdd(stats + threadIdx.x, v);
  }
}

// ---------------- Kernel E: h = lerp(Z) -> BN -> ReLU -> W2 -> out ----------------
// BN scale/shift derived from stats per block (no separate k_fin dispatch).
__global__ __launch_bounds__(256) void k_out(const float* __restrict__ Z, const float* __restrict__ W2,
                                             const float* __restrict__ b2, const float* __restrict__ gamma,
                                             const float* __restrict__ beta, const float* __restrict__ stats,
                                             float* __restrict__ out){
  __shared__ float sW2[CHH][CHH];
  __shared__ float sb2[CHH], ssc[CHH], ssh[CHH];
  for (int i = threadIdx.x; i < CHH * CHH; i += 256) sW2[i >> 4][i & 15] = W2[i];
  if (threadIdx.x < CHH){
    int o = threadIdx.x;
    const float inv = 1.0f / (float)(BB * (long long)LL);   // 1/409600
    float mu  = stats[o] * inv;
    float var = stats[16 + o] * inv - mu * mu;
    float sc  = gamma[o] * (1.0f / sqrtf(var + 1e-5f));
    ssc[o] = sc;
    ssh[o] = beta[o] - mu * sc;
    sb2[o] = b2[o];
  }
  __syncthreads();
  // XCD-contiguous block swizzle: 1600 blocks -> 8 XCDs x 200 contiguous (L2 reuse of Z slabs)
  int xcd = blockIdx.x & 7, loc = blockIdx.x >> 3;
  int eb = xcd * 200 + loc;
  int li  = eb * 256 + (int)threadIdx.x;   // 0..409599
  int b   = li / LL;
  int rem = li - b * LL;
  int to  = rem >> 9;
  int n   = rem & 511;
  int i0, i1; float w;
  lerp_coeff(to, i0, i1, w);
  const float* z0 = Z + ((size_t)((b * TT + i0) * NN + n)) * CHH;
  const float* z1 = Z + ((size_t)((b * TT + i1) * NN + n)) * CHH;
  float hr[CHH];
  #pragma unroll
  for (int c = 0; c < CHH; c += 4){
    float4 a = *reinterpret_cast<const float4*>(z0 + c);
    float4 d = *reinterpret_cast<const float4*>(z1 + c);
    float h0 = a.x + w * (d.x - a.x);
    float h1 = a.y + w * (d.y - a.y);
    float h2 = a.z + w * (d.z - a.z);
    float h3 = a.w + w * (d.w - a.w);
    hr[c]   = fmaxf(h0 * ssc[c]   + ssh[c],   0.0f);
    hr[c+1] = fmaxf(h1 * ssc[c+1] + ssh[c+1], 0.0f);
    hr[c+2] = fmaxf(h2 * ssc[c+2] + ssh[c+2], 0.0f);
    hr[c+3] = fmaxf(h3 * ssc[c+3] + ssh[c+3], 0.0f);
  }
  #pragma unroll
  for (int o2 = 0; o2 < CHH; ++o2){
    float v = sb2[o2];
    #pragma unroll
    for (int o = 0; o < CHH; ++o) v += sW2[o2][o] * hr[o];
    out[((size_t)(b * CHH + o2)) * LL + rem] = v;
  }
}

extern "C" void kernel_launch(void* const* d_in, const int* in_sizes, int n_in,
                              void* d_out, int out_size, void* d_ws, size_t ws_size,
                              hipStream_t stream){
  (void)in_sizes; (void)n_in; (void)out_size; (void)ws_size;
  const float* x     = (const float*)d_in[0];
  const int*   coord = (const int*)d_in[1];
  const float* Wf    = (const float*)d_in[2];
  const float* bfv   = (const float*)d_in[3];
  const float* Wr    = (const float*)d_in[4];
  const float* br    = (const float*)d_in[5];
  const float* W1    = (const float*)d_in[6];
  const float* b1    = (const float*)d_in[7];
  const float* gamma = (const float*)d_in[8];
  const float* beta  = (const float*)d_in[9];
  const float* W2    = (const float*)d_in[10];
  const float* b2    = (const float*)d_in[11];

  float* ws    = (float*)d_ws;
  float* r     = ws;                          // 524288 f32  (2 MB)
  float* Z     = ws + 524288;                 // 1048576 f32 (4 MB)
  float* stats = ws + 524288 + 1048576;       // 32 f32: [A1(16), A2(16)]

  float* out  = (float*)d_out;                // [B,16,L] = 6,553,600 f32
  float* outR = out + (size_t)BB * CHH * LL;  // [B,1,400,64,64] = 3,276,800 f32

  k_r   <<<512,  256, 0, stream>>>(x, Wr, br, r, stats);
  k_z   <<<1024, 256, 0, stream>>>(x, coord, Wf, bfv, W1, b1, Z);
  k_rm  <<<3456, 256, 0, stream>>>(r, outR, Z, stats);
  k_out <<<1600, 256, 0, stream>>>(Z, W2, b2, gamma, beta, stats, out);
}

// Round 7
// 177.058 us; speedup vs baseline: 1.0778x; 1.0128x over previous
//
#include <hip/hip_runtime.h>
#include <stdint.h>

// Problem constants (from setup_inputs; harness always uses these)
#define BB   2
#define CC   32      // input channels
#define TT   64      // input T
#define HWH  4096    // H*W = 64*64
#define NN   512     // coords per batch
#define CFF  32      // feat channels
#define CHH  16      // projection channels
#define TOUT 400     // featT == orgt == 400
#define LL   (TOUT*NN)  // 204800

__device__ __forceinline__ void lerp_coeff(int to, int& i0, int& i1, float& w){
  const float step = (float)(63.0 / 399.0);   // matches python (T-1)/(out_t-1) in f32
  float pos = (float)to * step;
  i0 = (int)floorf(pos);
  if (i0 > TT - 1) i0 = TT - 1;
  i1 = i0 + 1; if (i1 > TT - 1) i1 = TT - 1;
  w = pos - (float)i0;
}

// ---------------- Dispatch 1 (merged, disjoint block ranges — NOT intra-block fusion, R5 lesson):
//   blocks 0..511    : r[b][t][hw] = Wr.x + br          (coalesced stream, BW-bound)
//   blocks 512..1535 : Z[b][t][n][o] = Weff.x[coord]+bz (scattered gather, latency-bound)
// Independent work; co-resident waves overlap gather latency under the stream.
__global__ __launch_bounds__(256) void k_rz(const float* __restrict__ x, const float* __restrict__ Wr,
                                            const float* __restrict__ br, const int* __restrict__ coord,
                                            const float* __restrict__ Wf, const float* __restrict__ bfv,
                                            const float* __restrict__ W1, const float* __restrict__ b1,
                                            float* __restrict__ r, float* __restrict__ Z,
                                            float* __restrict__ stats){
  if (blockIdx.x < 512){
    // ---- r path ----
    if (blockIdx.x == 0 && threadIdx.x < 32) stats[threadIdx.x] = 0.f;
    int tid = blockIdx.x * 256 + threadIdx.x;   // 131072 threads, 4 hw each
    int hw0 = (tid & 1023) << 2;
    int t   = (tid >> 10) & 63;
    int b   = tid >> 16;
    float br0 = br[0];
    float4 acc = make_float4(br0, br0, br0, br0);
    const float* xp = x + ((size_t)(b * CC) * TT + t) * HWH + hw0;
    #pragma unroll
    for (int c = 0; c < CC; ++c){
      float4 v = *reinterpret_cast<const float4*>(xp + (size_t)c * TT * HWH);
      float w = Wr[c];
      acc.x += w * v.x;  acc.y += w * v.y;  acc.z += w * v.z;  acc.w += w * v.w;
    }
    *reinterpret_cast<float4*>(r + ((size_t)(b * TT + t)) * HWH + hw0) = acc;
    return;
  }
  // ---- Z path: Weff = W1.Wf computed per block (cheap); 4 lanes/element share x via shfl ----
  __shared__ float sWT[CC][CHH];    // Weff transposed: [c][o]
  __shared__ float scz[CHH];        // fused bias  W1.bf + b1
  for (int i = threadIdx.x; i < CHH * CC; i += 256){
    int o = i >> 5, c = i & 31;
    float v = 0.f;
    #pragma unroll
    for (int k = 0; k < CFF; ++k) v += W1[o * CFF + k] * Wf[k * CC + c];
    sWT[c][o] = v;
  }
  if (threadIdx.x < CHH){
    float v = b1[threadIdx.x];
    #pragma unroll
    for (int k = 0; k < CFF; ++k) v += W1[threadIdx.x * CFF + k] * bfv[k];
    scz[threadIdx.x] = v;
  }
  __syncthreads();
  int lane = threadIdx.x & 63;
  int sub  = threadIdx.x & 3;                        // quarter (channels in, outputs out)
  int e = ((int)blockIdx.x - 512) * 64 + ((int)threadIdx.x >> 2); // element 0..65535 = (b,t,n)
  int n = e & 511, t = (e >> 9) & 63, b = e >> 15;
  int h  = coord[(b * NN + n) * 2 + 0];
  int wq = coord[(b * NN + n) * 2 + 1];
  int hw = h * 64 + wq;
  const float* xp = x + (((size_t)(b * CC + sub * 8)) * TT + t) * HWH + hw;
  float xv[8];
  #pragma unroll
  for (int j = 0; j < 8; ++j) xv[j] = xp[(size_t)j * (TT * HWH)];
  float acc0 = scz[sub * 4], acc1 = scz[sub * 4 + 1], acc2 = scz[sub * 4 + 2], acc3 = scz[sub * 4 + 3];
  int grp = lane & ~3;
  #pragma unroll
  for (int j = 0; j < 8; ++j){
    #pragma unroll
    for (int src = 0; src < 4; ++src){
      float xc = __shfl(xv[j], grp + src, 64);   // channel c = src*8+j of this element
      int c = src * 8 + j;
      const float4 w4 = *reinterpret_cast<const float4*>(&sWT[c][sub * 4]);
      acc0 += w4.x * xc;  acc1 += w4.y * xc;  acc2 += w4.z * xc;  acc3 += w4.w * xc;
    }
  }
  *reinterpret_cast<float4*>(Z + ((size_t)((b * TT + t) * NN + n)) * CHH + sub * 4)
      = make_float4(acc0, acc1, acc2, acc3);
}

// ---------------- Dispatch 2: result lerp (blocks 0..3199) | moment accum (3200..3455) ----------------
// Moment part: A1[o] = sum_t q_t z_t[o];  A2[o] = sum_t a_t z_t[o]^2 + c_t z_t[o] z_{t+1}[o]
__global__ __launch_bounds__(256) void k_rm(const float* __restrict__ r, float* __restrict__ outR,
                                            const float* __restrict__ Z, float* __restrict__ stats){
  if (blockIdx.x < 3200){
    // ------- result = lerp_t(r) -------
    int tid = blockIdx.x * 256 + threadIdx.x;   // 819200 threads, 4 hw each
    int hw0  = (tid & 1023) << 2;
    int rest = tid >> 10;                       // 0..799 = b*400+to
    int b  = rest >= TOUT ? 1 : 0;
    int to = rest - b * TOUT;
    int i0, i1; float w;
    lerp_coeff(to, i0, i1, w);
    float4 a = *reinterpret_cast<const float4*>(r + ((size_t)(b * TT + i0)) * HWH + hw0);
    float4 c = *reinterpret_cast<const float4*>(r + ((size_t)(b * TT + i1)) * HWH + hw0);
    float4 o;
    o.x = a.x + w * (c.x - a.x);
    o.y = a.y + w * (c.y - a.y);
    o.z = a.z + w * (c.z - a.z);
    o.w = a.w + w * (c.w - a.w);
    *reinterpret_cast<float4*>(outR + ((size_t)(b * TOUT + to)) * HWH + hw0) = o;
    return;
  }
  // ------- moment accumulation -------
  __shared__ float sco[192];        // q[64], a[64], c[64]
  __shared__ float red[4][32];
  if (threadIdx.x < 192) sco[threadIdx.x] = 0.f;
  __syncthreads();
  for (int to = threadIdx.x; to < TOUT; to += 256){
    int i0, i1; float w;
    lerp_coeff(to, i0, i1, w);
    if (i1 == i0){
      atomicAdd(&sco[i0], 1.f);  atomicAdd(&sco[64 + i0], 1.f);
    } else {
      float u = 1.f - w;
      atomicAdd(&sco[i0], u);        atomicAdd(&sco[64 + i0], u * u);
      atomicAdd(&sco[i1], w);        atomicAdd(&sco[64 + i1], w * w);
      atomicAdd(&sco[128 + i0], 2.f * w * u);
    }
  }
  __syncthreads();
  int t = threadIdx.x & 63;                                  // lane == t (shfl cross-term)
  int e = (blockIdx.x - 3200) * 4 + ((int)threadIdx.x >> 6); // (b,n) 0..1023
  int b = e >> 9, n = e & 511;
  const float* zp = Z + ((size_t)((b * TT + t) * NN + n)) * CHH;
  float z[CHH];
  #pragma unroll
  for (int c = 0; c < CHH; c += 4){
    float4 v = *reinterpret_cast<const float4*>(zp + c);
    z[c] = v.x; z[c+1] = v.y; z[c+2] = v.z; z[c+3] = v.w;
  }
  float qt = sco[t], at = sco[64 + t], ct = sco[128 + t];   // ct==0 at t=63 structurally
  float v1[CHH], v2[CHH];
  #pragma unroll
  for (int o = 0; o < CHH; ++o){
    float zn = __shfl_down(z[o], 1, 64);            // z at t+1 (same b,n)
    v1[o] = qt * z[o];
    v2[o] = at * z[o] * z[o] + ct * z[o] * zn;
  }
  #pragma unroll
  for (int o = 0; o < CHH; ++o){
    #pragma unroll
    for (int s = 32; s > 0; s >>= 1){
      v1[o] += __shfl_down(v1[o], s, 64);
      v2[o] += __shfl_down(v2[o], s, 64);
    }
  }
  int wave = threadIdx.x >> 6, lane = threadIdx.x & 63;
  if (lane == 0){
    #pragma unroll
    for (int o = 0; o < CHH; ++o){ red[wave][o] = v1[o]; red[wave][16 + o] = v2[o]; }
  }
  __syncthreads();
  if (threadIdx.x < 32){
    float v = red[0][threadIdx.x] + red[1][threadIdx.x] + red[2][threadIdx.x] + red[3][threadIdx.x];
    atomicAdd(stats + threadIdx.x, v);
  }
}

// ---------------- Dispatch 3: h = lerp(Z) -> BN -> ReLU -> W2 -> out ----------------
// BN scale/shift derived from stats per block (no separate k_fin dispatch).
__global__ __launch_bounds__(256) void k_out(const float* __restrict__ Z, const float* __restrict__ W2,
                                             const float* __restrict__ b2, const float* __restrict__ gamma,
                                             const float* __restrict__ beta, const float* __restrict__ stats,
                                             float* __restrict__ out){
  __shared__ float sW2[CHH][CHH];
  __shared__ float sb2[CHH], ssc[CHH], ssh[CHH];
  for (int i = threadIdx.x; i < CHH * CHH; i += 256) sW2[i >> 4][i & 15] = W2[i];
  if (threadIdx.x < CHH){
    int o = threadIdx.x;
    const float inv = 1.0f / (float)(BB * (long long)LL);   // 1/409600
    float mu  = stats[o] * inv;
    float var = stats[16 + o] * inv - mu * mu;
    float sc  = gamma[o] * (1.0f / sqrtf(var + 1e-5f));
    ssc[o] = sc;
    ssh[o] = beta[o] - mu * sc;
    sb2[o] = b2[o];
  }
  __syncthreads();
  // XCD-contiguous block swizzle: 1600 blocks -> 8 XCDs x 200 contiguous (L2 reuse of Z slabs)
  int xcd = blockIdx.x & 7, loc = blockIdx.x >> 3;
  int eb = xcd * 200 + loc;
  int li  = eb * 256 + (int)threadIdx.x;   // 0..409599
  int b   = li / LL;
  int rem = li - b * LL;
  int to  = rem >> 9;
  int n   = rem & 511;
  int i0, i1; float w;
  lerp_coeff(to, i0, i1, w);
  const float* z0 = Z + ((size_t)((b * TT + i0) * NN + n)) * CHH;
  const float* z1 = Z + ((size_t)((b * TT + i1) * NN + n)) * CHH;
  float hr[CHH];
  #pragma unroll
  for (int c = 0; c < CHH; c += 4){
    float4 a = *reinterpret_cast<const float4*>(z0 + c);
    float4 d = *reinterpret_cast<const float4*>(z1 + c);
    float h0 = a.x + w * (d.x - a.x);
    float h1 = a.y + w * (d.y - a.y);
    float h2 = a.z + w * (d.z - a.z);
    float h3 = a.w + w * (d.w - a.w);
    hr[c]   = fmaxf(h0 * ssc[c]   + ssh[c],   0.0f);
    hr[c+1] = fmaxf(h1 * ssc[c+1] + ssh[c+1], 0.0f);
    hr[c+2] = fmaxf(h2 * ssc[c+2] + ssh[c+2], 0.0f);
    hr[c+3] = fmaxf(h3 * ssc[c+3] + ssh[c+3], 0.0f);
  }
  #pragma unroll
  for (int o2 = 0; o2 < CHH; ++o2){
    float v = sb2[o2];
    #pragma unroll
    for (int o = 0; o < CHH; ++o) v += sW2[o2][o] * hr[o];
    out[((size_t)(b * CHH + o2)) * LL + rem] = v;
  }
}

extern "C" void kernel_launch(void* const* d_in, const int* in_sizes, int n_in,
                              void* d_out, int out_size, void* d_ws, size_t ws_size,
                              hipStream_t stream){
  (void)in_sizes; (void)n_in; (void)out_size; (void)ws_size;
  const float* x     = (const float*)d_in[0];
  const int*   coord = (const int*)d_in[1];
  const float* Wf    = (const float*)d_in[2];
  const float* bfv   = (const float*)d_in[3];
  const float* Wr    = (const float*)d_in[4];
  const float* br    = (const float*)d_in[5];
  const float* W1    = (const float*)d_in[6];
  const float* b1    = (const float*)d_in[7];
  const float* gamma = (const float*)d_in[8];
  const float* beta  = (const float*)d_in[9];
  const float* W2    = (const float*)d_in[10];
  const float* b2    = (const float*)d_in[11];

  float* ws    = (float*)d_ws;
  float* r     = ws;                          // 524288 f32  (2 MB)
  float* Z     = ws + 524288;                 // 1048576 f32 (4 MB)
  float* stats = ws + 524288 + 1048576;       // 32 f32: [A1(16), A2(16)]

  float* out  = (float*)d_out;                // [B,16,L] = 6,553,600 f32
  float* outR = out + (size_t)BB * CHH * LL;  // [B,1,400,64,64] = 3,276,800 f32

  k_rz  <<<1536, 256, 0, stream>>>(x, Wr, br, coord, Wf, bfv, W1, b1, r, Z, stats);
  k_rm  <<<3456, 256, 0, stream>>>(r, outR, Z, stats);
  k_out <<<1600, 256, 0, stream>>>(Z, W2, b2, gamma, beta, stats, out);
}